// Round 4
// baseline (77.615 us; speedup 1.0000x reference)
//
#include <hip/hip_runtime.h>
#include <math.h>

#define LENL 96
#define NCH 32
#define CCH 16
#define NEXP 4
#define NB 512
#define SPLIT 8
#define TWO_PI_D 6.283185307179586476925286766559
#define PADX 98   // xd row stride in doubles (16B-aligned rows)
#define PADM 49

// ---------------- Kernel 1: gather + Goertzel DFT + top-3 (8 series/block) ----------------
// grid = NB*4 blocks of 128. Block (b,q) handles series n0=8q..8q+7 of row b.
// Wave w (0,1) handles 4 series; lane = freq-1 (47 active).
__global__ __launch_bounds__(128) void k1_dft(
    const float* __restrict__ x,        // (512,96,32,16)
    const float* __restrict__ W_start,  // (1,32)
    float* __restrict__ yPart,          // (2048,96) partial y
    float2* __restrict__ selAB,         // (512*32*3)
    int* __restrict__ selFq)            // (512*32*3)
{
    const int blk = blockIdx.x;
    const int b = blk >> 2, q = blk & 3;
    const int n0 = q << 3;
    const int t = threadIdx.x;
    const int w = t >> 6, lane = t & 63;

    __shared__ __align__(16) double xd[8][PADX];
    __shared__ double mags[8][PADM];
    __shared__ float reF[8][PADM], imF[8][PADM];

    for (int idx = t; idx < 8 * LENL; idx += 128) {
        int l = idx >> 3, n = idx & 7;
        xd[n][l] = (double)x[(((size_t)b * LENL + l) * NCH + (n0 + n)) * CCH];
    }
    __syncthreads();

    if (lane < 47) {
        const double w0 = TWO_PI_D * (double)(lane + 1) / 96.0;
        const double c2 = 2.0 * cos(w0);
        double s1a = 0, s2a = 0, s1b = 0, s2b = 0;
        double s1c = 0, s2c = 0, s1d = 0, s2d = 0;
        const double2* pa = (const double2*)&xd[w * 4 + 0][0];
        const double2* pb = (const double2*)&xd[w * 4 + 1][0];
        const double2* pc = (const double2*)&xd[w * 4 + 2][0];
        const double2* pd = (const double2*)&xd[w * 4 + 3][0];
        #pragma unroll 2
        for (int j = 0; j < 48; ++j) {
            double2 va = pa[j], vb = pb[j], vc = pc[j], vd = pd[j];
            double tt;
            tt = fma(c2, s1a, va.x - s2a); s2a = s1a; s1a = tt;
            tt = fma(c2, s1b, vb.x - s2b); s2b = s1b; s1b = tt;
            tt = fma(c2, s1c, vc.x - s2c); s2c = s1c; s1c = tt;
            tt = fma(c2, s1d, vd.x - s2d); s2d = s1d; s1d = tt;
            tt = fma(c2, s1a, va.y - s2a); s2a = s1a; s1a = tt;
            tt = fma(c2, s1b, vb.y - s2b); s2b = s1b; s1b = tt;
            tt = fma(c2, s1c, vc.y - s2c); s2c = s1c; s1c = tt;
            tt = fma(c2, s1d, vd.y - s2d); s2d = s1d; s1d = tt;
        }
        const double cw = cos(w0), sw = sin(w0);
        #define GFIN(S1, S2, ROW) { \
            double yr = (S1) - cw * (S2); \
            double yi = sw * (S2); \
            double Xr = cw * yr - sw * yi; \
            double Xi = cw * yi + sw * yr; \
            mags[ROW][lane] = Xr * Xr + Xi * Xi; \
            reF[ROW][lane] = (float)Xr; imF[ROW][lane] = (float)Xi; }
        GFIN(s1a, s2a, w * 4 + 0)
        GFIN(s1b, s2b, w * 4 + 1)
        GFIN(s1c, s2c, w * 4 + 2)
        GFIN(s1d, s2d, w * 4 + 3)
        #undef GFIN
    }
    __syncthreads();

    if (t < 8) {
        double m1 = -1.0, m2 = -1.0, m3 = -1.0;
        int i1 = 0, i2 = 0, i3 = 0;
        for (int fi = 0; fi < 47; ++fi) {
            double mg = mags[t][fi];
            if (mg > m1)      { m3 = m2; i3 = i2; m2 = m1; i2 = i1; m1 = mg; i1 = fi; }
            else if (mg > m2) { m3 = m2; i3 = i2; m2 = mg; i2 = fi; }
            else if (mg > m3) { m3 = mg; i3 = fi; }
        }
        const int n = n0 + t;
        const float sc = W_start[n] * (2.0f / 96.0f);
        const size_t base = ((size_t)b * NCH + n) * 3;
        selFq[base + 0] = i1 + 1; selAB[base + 0] = make_float2(sc * reF[t][i1], sc * imF[t][i1]);
        selFq[base + 1] = i2 + 1; selAB[base + 1] = make_float2(sc * reF[t][i2], sc * imF[t][i2]);
        selFq[base + 2] = i3 + 1; selAB[base + 2] = make_float2(sc * reF[t][i3], sc * imF[t][i3]);
    }

    if (t < LENL) {
        float yv = 0.f;
        #pragma unroll
        for (int n = 0; n < 8; ++n)
            yv += (float)xd[n][t] * W_start[n0 + n];
        yPart[(size_t)blk * LENL + t] = yv;
    }
}

// ---------------- Kernel 2: trend + seasonal + logits + gates + M (per b) ----------------
__global__ __launch_bounds__(128) void k2_gate(
    const float* __restrict__ yPart,
    const float2* __restrict__ selAB,
    const int* __restrict__ selFq,
    const float* __restrict__ b_start,
    const float* __restrict__ W_gate,   // (4,96)
    const float* __restrict__ b_gate,   // (4,)
    const float* __restrict__ W_exp,    // (4,16,16)
    const float* __restrict__ b_exp,    // (4,16)
    float* __restrict__ Mws, float* __restrict__ biasws, float* __restrict__ gws)
{
    const int b = blockIdx.x, t = threadIdx.x;
    __shared__ float2 twf[LENL];
    __shared__ float As[96], Bs[96];
    __shared__ int Fs[96];
    __shared__ float g_sh[LENL];
    __shared__ float logit_s[NEXP];
    __shared__ float gsel[2];
    __shared__ int esel[2];

    if (t < LENL) {
        double ang = TWO_PI_D * (double)t / 96.0;
        twf[t] = make_float2((float)cos(ang), (float)(-sin(ang)));
        float2 ab = selAB[(size_t)b * 96 + t];
        As[t] = ab.x; Bs[t] = ab.y;
        Fs[t] = selFq[(size_t)b * 96 + t];
        g_sh[t] = yPart[((size_t)b * 4 + 0) * LENL + t]
                + yPart[((size_t)b * 4 + 1) * LENL + t]
                + yPart[((size_t)b * 4 + 2) * LENL + t]
                + yPart[((size_t)b * 4 + 3) * LENL + t];
    }
    __syncthreads();

    float gval = 0.f;
    if (t < LENL) {
        float s4 = 0.f;
        #pragma unroll
        for (int j = -1; j <= 2; ++j) {
            int li = t + j; li = li < 0 ? 0 : (li > 95 ? 95 : li);
            s4 += g_sh[li];
        }
        float s8 = s4;
        {
            int li;
            li = t - 3; li = li < 0 ? 0 : li; s8 += g_sh[li];
            li = t - 2; li = li < 0 ? 0 : li; s8 += g_sh[li];
            li = t + 3; li = li > 95 ? 95 : li; s8 += g_sh[li];
            li = t + 4; li = li > 95 ? 95 : li; s8 += g_sh[li];
        }
        float s12 = s8;
        {
            int li;
            li = t - 5; li = li < 0 ? 0 : li; s12 += g_sh[li];
            li = t - 4; li = li < 0 ? 0 : li; s12 += g_sh[li];
            li = t + 5; li = li > 95 ? 95 : li; s12 += g_sh[li];
            li = t + 6; li = li > 95 ? 95 : li; s12 += g_sh[li];
        }
        float tr = (s4 * 0.25f + s8 * 0.125f + s12 * (1.f / 12.f)) * (1.f / 3.f);
        float se = 0.f;
        for (int k = 0; k < 96; ++k) {
            int m = (Fs[k] * t) % LENL;
            float2 c = twf[m];
            se += As[k] * c.x + Bs[k] * c.y;
        }
        gval = g_sh[t] + tr + se + b_start[0];
    }
    __syncthreads();
    if (t < LENL) g_sh[t] = gval;
    __syncthreads();

    if (t < NEXP) {
        float acc = b_gate[t];
        for (int l = 0; l < LENL; ++l) acc += g_sh[l] * W_gate[t * LENL + l];
        logit_s[t] = acc;
    }
    __syncthreads();

    if (t == 0) {
        int i1 = 0;
        for (int e = 1; e < NEXP; ++e) if (logit_s[e] > logit_s[i1]) i1 = e;
        int i2 = (i1 == 0) ? 1 : 0;
        for (int e = 0; e < NEXP; ++e) if (e != i1 && logit_s[e] > logit_s[i2]) i2 = e;
        float v1 = logit_s[i1], v2 = logit_s[i2];
        float e2v = expf(v2 - v1);
        float inv = 1.f / (1.f + e2v);
        esel[0] = i1; esel[1] = i2; gsel[0] = inv; gsel[1] = e2v * inv;
        for (int e = 0; e < NEXP; ++e)
            gws[b * NEXP + e] = (e == i1) ? inv : ((e == i2) ? e2v * inv : 0.f);
    }
    __syncthreads();

    {
        float ga = gsel[0], gb = gsel[1];
        int ea = esel[0], eb = esel[1];
        for (int idx = t; idx < CCH * CCH; idx += 128)
            Mws[b * 256 + idx] = ga * W_exp[ea * 256 + idx] + gb * W_exp[eb * 256 + idx];
        if (t < CCH)
            biasws[b * CCH + t] = ga * b_exp[ea * CCH + t] + gb * b_exp[eb * CCH + t];
    }
}

// ---------------- Kernel 3: out = x + x @ M_b + bias_b ----------------
__global__ __launch_bounds__(256) void k2_out(
    const float* __restrict__ x,
    const float* __restrict__ Mws,
    const float* __restrict__ biasws,
    float* __restrict__ out)
{
    const int blk = blockIdx.x;
    const int b = blk >> 3;
    const int chunk = blk & 7;
    const int t = threadIdx.x;
    const int lane = t & 63;
    const int wv = t >> 6;
    const int cg = lane & 3;
    const int prow = (wv << 4) + (lane >> 2);

    const float* Mb = Mws + b * 256 + cg * 4;
    float4 m0  = *(const float4*)(Mb + 0 * 16);
    float4 m1  = *(const float4*)(Mb + 1 * 16);
    float4 m2  = *(const float4*)(Mb + 2 * 16);
    float4 m3  = *(const float4*)(Mb + 3 * 16);
    float4 m4  = *(const float4*)(Mb + 4 * 16);
    float4 m5  = *(const float4*)(Mb + 5 * 16);
    float4 m6  = *(const float4*)(Mb + 6 * 16);
    float4 m7  = *(const float4*)(Mb + 7 * 16);
    float4 m8  = *(const float4*)(Mb + 8 * 16);
    float4 m9  = *(const float4*)(Mb + 9 * 16);
    float4 m10 = *(const float4*)(Mb + 10 * 16);
    float4 m11 = *(const float4*)(Mb + 11 * 16);
    float4 m12 = *(const float4*)(Mb + 12 * 16);
    float4 m13 = *(const float4*)(Mb + 13 * 16);
    float4 m14 = *(const float4*)(Mb + 14 * 16);
    float4 m15 = *(const float4*)(Mb + 15 * 16);
    float4 bias = *(const float4*)(biasws + b * CCH + cg * 4);

    const size_t base = (size_t)b * (LENL * NCH * CCH);
    const float* xb = x + base;
    float* ob = out + base;
    const int posBase = chunk * (LENL * NCH / SPLIT);

    #pragma unroll
    for (int i = 0; i < (LENL * NCH / SPLIT) / 64; ++i) {
        int pos = posBase + i * 64 + prow;
        const float* xr = xb + (size_t)pos * CCH;
        float4 x0 = *(const float4*)(xr + 0);
        float4 x1 = *(const float4*)(xr + 4);
        float4 x2 = *(const float4*)(xr + 8);
        float4 x3 = *(const float4*)(xr + 12);
        float4 acc = bias;
        #define STEPF(v, M) acc.x += (v) * (M).x; acc.y += (v) * (M).y; acc.z += (v) * (M).z; acc.w += (v) * (M).w;
        STEPF(x0.x, m0)  STEPF(x0.y, m1)  STEPF(x0.z, m2)  STEPF(x0.w, m3)
        STEPF(x1.x, m4)  STEPF(x1.y, m5)  STEPF(x1.z, m6)  STEPF(x1.w, m7)
        STEPF(x2.x, m8)  STEPF(x2.y, m9)  STEPF(x2.z, m10) STEPF(x2.w, m11)
        STEPF(x3.x, m12) STEPF(x3.y, m13) STEPF(x3.z, m14) STEPF(x3.w, m15)
        #undef STEPF
        float4 xo = (cg == 0) ? x0 : ((cg == 1) ? x1 : ((cg == 2) ? x2 : x3));
        acc.x += xo.x; acc.y += xo.y; acc.z += xo.z; acc.w += xo.w;
        *(float4*)(ob + (size_t)pos * CCH + cg * 4) = acc;
    }
}

// ---------------- Kernel 4: balance loss ----------------
__global__ __launch_bounds__(256) void k3_loss(
    const float* __restrict__ gws, float* __restrict__ loss_out)
{
    __shared__ float sh[8][256];
    const int t = threadIdx.x;
    float imp[4] = {0, 0, 0, 0}, ld[4] = {0, 0, 0, 0};
    for (int b = t; b < NB; b += 256) {
        #pragma unroll
        for (int e = 0; e < 4; ++e) {
            float v = gws[b * 4 + e];
            imp[e] += v;
            ld[e] += (v > 0.f) ? 1.f : 0.f;
        }
    }
    #pragma unroll
    for (int e = 0; e < 4; ++e) { sh[e][t] = imp[e]; sh[4 + e][t] = ld[e]; }
    __syncthreads();
    if (t < 8) {
        float s = 0.f;
        for (int i = 0; i < 256; ++i) s += sh[t][i];
        sh[t][0] = s;
    }
    __syncthreads();
    if (t == 0) {
        float a = sh[0][0], b2 = sh[1][0], c = sh[2][0], d = sh[3][0];
        float mean = (a + b2 + c + d) * 0.25f;
        float var = ((a - mean) * (a - mean) + (b2 - mean) * (b2 - mean) +
                     (c - mean) * (c - mean) + (d - mean) * (d - mean)) * (1.f / 3.f);
        float L1 = var / (mean * mean + 1e-10f);
        a = sh[4][0]; b2 = sh[5][0]; c = sh[6][0]; d = sh[7][0];
        mean = (a + b2 + c + d) * 0.25f;
        var = ((a - mean) * (a - mean) + (b2 - mean) * (b2 - mean) +
               (c - mean) * (c - mean) + (d - mean) * (d - mean)) * (1.f / 3.f);
        float L2 = var / (mean * mean + 1e-10f);
        *loss_out = 0.01f * (L1 + L2);
    }
}

extern "C" void kernel_launch(void* const* d_in, const int* in_sizes, int n_in,
                              void* d_out, int out_size, void* d_ws, size_t ws_size,
                              hipStream_t stream)
{
    const float* x       = (const float*)d_in[0];
    const float* W_start = (const float*)d_in[1];
    const float* b_start = (const float*)d_in[2];
    const float* W_gate  = (const float*)d_in[3];
    const float* b_gate  = (const float*)d_in[4];
    const float* W_exp   = (const float*)d_in[5];
    const float* b_exp   = (const float*)d_in[6];
    float* out = (float*)d_out;

    float* ws = (float*)d_ws;
    float* yPart   = ws;                                 // 2048*96 = 196,608
    float2* selAB  = (float2*)(ws + 196608);             // 49,152 float2
    int* selFq     = (int*)(ws + 196608 + 98304);        // 49,152 int
    float* Mws     = ws + 196608 + 98304 + 49152;        // 131,072
    float* biasws  = Mws + NB * 256;                     // 8,192
    float* gws     = biasws + NB * CCH;                  // 2,048

    k1_dft<<<NB * 4, 128, 0, stream>>>(x, W_start, yPart, selAB, selFq);
    k2_gate<<<NB, 128, 0, stream>>>(yPart, selAB, selFq, b_start,
                                    W_gate, b_gate, W_exp, b_exp, Mws, biasws, gws);
    k2_out<<<NB * SPLIT, 256, 0, stream>>>(x, Mws, biasws, out);
    k3_loss<<<1, 256, 0, stream>>>(gws, out + (size_t)out_size - 1);
}